// Round 9
// baseline (253.389 us; speedup 1.0000x reference)
//
#include <hip/hip_runtime.h>

#define NSRC 1024
#define MTGT 16384
#define DDIM 768
#define MAXIT 100
#define NBLK 256
#define NTHR 1024
#define NGRP 16
#define GRPSZ 16

typedef __attribute__((ext_vector_type(8))) short bf16x8;
typedef __attribute__((ext_vector_type(4))) float f32x4;
typedef __attribute__((ext_vector_type(4))) unsigned short u16x4;
typedef __attribute__((ext_vector_type(8))) unsigned short u16x8;

__device__ __forceinline__ unsigned short f2bf(float f) {
  unsigned u = __float_as_uint(f);
  u += 0x7FFFu + ((u >> 16) & 1u);
  return (unsigned short)(u >> 16);
}
__device__ __forceinline__ float bf2f(unsigned short h) {
  return __uint_as_float(((unsigned)h) << 16);
}
__device__ __forceinline__ void gstoref(float* p, float x) {
  __hip_atomic_store(p, x, __ATOMIC_RELAXED, __HIP_MEMORY_SCOPE_AGENT);
}
__device__ __forceinline__ float gloadf(const float* p) {
  return __hip_atomic_load(p, __ATOMIC_RELAXED, __HIP_MEMORY_SCOPE_AGENT);
}
__device__ __forceinline__ unsigned gloadu(const unsigned* p) {
  return __hip_atomic_load(p, __ATOMIC_RELAXED, __HIP_MEMORY_SCOPE_AGENT);
}

// ---------------- kernel 1: prep — A fp32->bf16, ssq, zero ctrl ----------------
__global__ __launch_bounds__(256) void ot_prep_kernel(
    const float* __restrict__ src, unsigned short* __restrict__ Ab,
    float* __restrict__ ssq, unsigned* __restrict__ ctrl) {
  const int gid = blockIdx.x * 256 + threadIdx.x;  // 65536 threads
  #pragma unroll
  for (int k = 0; k < 3; ++k) {
    int idx = gid + k * 65536;
    float4 a = *(const float4*)(src + (size_t)idx * 4);
    u16x4 b; b[0] = f2bf(a.x); b[1] = f2bf(a.y); b[2] = f2bf(a.z); b[3] = f2bf(a.w);
    *(u16x4*)(Ab + (size_t)idx * 4) = b;
  }
  {
    int row = gid >> 6, l = gid & 63;
    float s = 0.f;
    #pragma unroll
    for (int k = 0; k < 3; ++k) {
      float4 a = *(const float4*)(src + (size_t)row * DDIM + (l + k * 64) * 4);
      s += a.x * a.x + a.y * a.y + a.z * a.z + a.w * a.w;
    }
    #pragma unroll
    for (int off = 32; off > 0; off >>= 1) s += __shfl_down(s, off, 64);
    if (l == 0) ssq[row] = s;
  }
  if (gid < 4096) ctrl[gid] = 0u;
}

// ---------------- kernel 2: GEMM — full B-panel in LDS, barrier-free MFMA ----------------
// 256 blocks x 1024 thr (16 waves). Block owns cols bid*64..+63 (output 1024x64).
// B (64 x 768 fp32 -> bf16, 96 KB) staged ONCE; A read from L2 (1.5 MB, replicated).
__global__ __launch_bounds__(NTHR) void ot_gemm_kernel(
    const float* __restrict__ tgt, const unsigned short* __restrict__ Ab,
    const float* __restrict__ ssq,
    unsigned short* __restrict__ Kb, float* __restrict__ Kvp) {
  __shared__ __align__(16) unsigned short Bs[64 * 768];  // 96 KB, XOR-swizzled
  __shared__ float tsql[64];
  const int tid = threadIdx.x, bid = blockIdx.x;
  const int w = tid >> 6, l = tid & 63;
  const int lr = l & 15, hi = l >> 4;
  const int m0 = w * 64;

  // ---- stage full B panel: 6 x 16B chunks per thread ----
  #pragma unroll
  for (int q = 0; q < 6; ++q) {
    int idx2 = tid + q * 1024;            // 0..6143 = 64 rows x 96 chunks
    int rb = idx2 / 96, ch = idx2 % 96;
    int kts = ch >> 3, m = ch & 7;
    const float* gp = tgt + (size_t)(bid * 64 + rb) * DDIM + ch * 8;
    float4 f0 = *(const float4*)gp;
    float4 f1 = *(const float4*)(gp + 4);
    u16x8 bb;
    bb[0] = f2bf(f0.x); bb[1] = f2bf(f0.y); bb[2] = f2bf(f0.z); bb[3] = f2bf(f0.w);
    bb[4] = f2bf(f1.x); bb[5] = f2bf(f1.y); bb[6] = f2bf(f1.z); bb[7] = f2bf(f1.w);
    *(u16x8*)(&Bs[rb * 768 + (kts * 8 + (m ^ (rb & 7))) * 8]) = bb;
  }
  __syncthreads();

  // ---- tsq from staged B (bf16-rounded; error ~1e-4 rel, negligible) ----
  {
    int rw = w * 4 + hi;  // wave covers 4 rows, 16 lanes (lr) each
    float s = 0.f;
    #pragma unroll
    for (int j = 0; j < 6; ++j) {
      int ch = lr + j * 16;
      int kts = ch >> 3, m = ch & 7;
      u16x8 k8 = *(const u16x8*)(&Bs[rw * 768 + (kts * 8 + (m ^ (rw & 7))) * 8]);
      #pragma unroll
      for (int e = 0; e < 8; ++e) { float x = bf2f(k8[e]); s += x * x; }
    }
    s += __shfl_xor(s, 1, 64); s += __shfl_xor(s, 2, 64);
    s += __shfl_xor(s, 4, 64); s += __shfl_xor(s, 8, 64);
    if (lr == 0) tsql[rw] = s;
  }

  // ---- MFMA main loop: NO barriers; wave w computes rows m0..m0+63 ----
  f32x4 acc[4][4];
  #pragma unroll
  for (int fi = 0; fi < 4; ++fi)
    #pragma unroll
    for (int fj = 0; fj < 4; ++fj) acc[fi][fj] = (f32x4){0.f, 0.f, 0.f, 0.f};

  for (int kt = 0; kt < 12; ++kt) {
    #pragma unroll
    for (int kc = 0; kc < 2; ++kc) {
      bf16x8 a[4], b[4];
      #pragma unroll
      for (int fi = 0; fi < 4; ++fi)
        a[fi] = *(const bf16x8*)(Ab + (size_t)(m0 + fi * 16 + lr) * DDIM +
                                 kt * 64 + kc * 32 + hi * 8);
      #pragma unroll
      for (int fj = 0; fj < 4; ++fj) {
        int rb = fj * 16 + lr;
        b[fj] = *(const bf16x8*)(&Bs[rb * 768 + (kt * 8 + ((kc * 4 + hi) ^ (rb & 7))) * 8]);
      }
      #pragma unroll
      for (int fi = 0; fi < 4; ++fi)
        #pragma unroll
        for (int fj = 0; fj < 4; ++fj)
          acc[fi][fj] = __builtin_amdgcn_mfma_f32_16x16x32_bf16(a[fi], b[fj], acc[fi][fj], 0, 0, 0);
    }
  }
  __syncthreads();  // tsql (all waves) visible for epilogue

  // ---- epilogue: K = exp2(-SC*cost) -> global bf16; rowsum partials ----
  const float SC = 14.426950408889634f;  // log2(e)/0.1
  #pragma unroll
  for (int fi = 0; fi < 4; ++fi) {
    #pragma unroll
    for (int e = 0; e < 4; ++e) {
      int row = m0 + fi * 16 + hi * 4 + e;
      float sq = ssq[row];
      float p = 0.f;
      #pragma unroll
      for (int fj = 0; fj < 4; ++fj) {
        int col = bid * 64 + fj * 16 + lr;
        float cost = sq + tsql[fj * 16 + lr] - 2.0f * acc[fi][fj][e];
        float k = exp2f(-SC * cost);
        Kb[(size_t)row * MTGT + col] = f2bf(k);
        p += k;
      }
      p += __shfl_xor(p, 1, 64); p += __shfl_xor(p, 2, 64);
      p += __shfl_xor(p, 4, 64); p += __shfl_xor(p, 8, 64);
      if (lr == 0) Kvp[(size_t)bid * NSRC + row] = p;  // rowsum partial (it-0 Kv)
    }
  }
}

// ---------------- fence-free two-level tree barrier (monotonic) ----------------
__device__ __forceinline__ void grid_barrier(unsigned* garr, unsigned* root,
                                             unsigned* gen, unsigned& t) {
  __syncthreads();
  if (threadIdx.x == 0) {
    asm volatile("s_waitcnt vmcnt(0)" ::: "memory");
    unsigned g = (unsigned)(blockIdx.x >> 4);
    unsigned old = __hip_atomic_fetch_add(&garr[g * 64], 1u, __ATOMIC_RELAXED,
                                          __HIP_MEMORY_SCOPE_AGENT);
    if (old == t * GRPSZ + (GRPSZ - 1)) {
      unsigned r = __hip_atomic_fetch_add(root, 1u, __ATOMIC_RELAXED,
                                          __HIP_MEMORY_SCOPE_AGENT);
      if (r == t * NGRP + (NGRP - 1)) {
        __hip_atomic_store(gen, t + 1u, __ATOMIC_RELAXED, __HIP_MEMORY_SCOPE_AGENT);
      } else {
        while (gloadu(gen) < t + 1u) __builtin_amdgcn_s_sleep(1);
      }
    } else {
      while (gloadu(gen) < t + 1u) __builtin_amdgcn_s_sleep(1);
    }
    t += 1u;
  }
  __syncthreads();
}

// ---------------- kernel 3: Sinkhorn (K from global) + fused final ----------------
// 256 blocks x 1024 thr. Block owns cols bid*64..+63 (same map as GEMM writer).
__global__ __launch_bounds__(NTHR) void ot_sinkhorn_kernel(
    const unsigned short* __restrict__ Kb, float* Kvp, float* Kvf,
    float* otp, float* __restrict__ out,
    unsigned* garr, unsigned* root, unsigned* gen) {
  __shared__ float ulds[NSRC];
  __shared__ float vlds[64];
  __shared__ float red[1088];
  __shared__ float wred[1088];
  __shared__ int sflag;
  const int tid = threadIdx.x, bid = blockIdx.x;
  const int w = tid >> 6, l = tid & 63;
  const int r8 = l >> 3, c8 = l & 7;
  unsigned bt = 0;
  const float A_VAL = 1.0f / NSRC, B_VAL = 1.0f / MTGT;

  // ---- reduce GEMM's rowsum partials -> Kvf (= Kv at it 0, since v=1) ----
  {
    float s = gloadf(&Kvp[(size_t)(tid >> 2) * NSRC + (bid << 2) + (tid & 3)]);
    s += __shfl_xor(s, 4, 64);  s += __shfl_xor(s, 8, 64);
    s += __shfl_xor(s, 16, 64); s += __shfl_xor(s, 32, 64);
    if (l < 4) red[w * 4 + l] = s;
    __syncthreads();
    if (tid < 4) {
      float t = 0.f;
      #pragma unroll
      for (int g = 0; g < 16; ++g) t += red[g * 4 + tid];
      gstoref(&Kvf[(bid << 2) + tid], t);
    }
  }
  grid_barrier(garr, root, gen, bt);

  float uold = 1.0f;
  for (int it = 0; it < MAXIT; ++it) {
    // ---- u update + convergence (redundant, bitwise-uniform) ----
    {
      float kv = gloadf(&Kvf[tid]);
      float un = A_VAL / (kv + 1e-10f);
      float d = fabsf(un - uold);
      #pragma unroll
      for (int off = 32; off > 0; off >>= 1) d = fmaxf(d, __shfl_xor(d, off, 64));
      if (l == 0) red[w] = d;
      ulds[tid] = un;
      uold = un;
    }
    __syncthreads();
    if (tid == 0) {
      float dm = red[0];
      #pragma unroll
      for (int k = 1; k < 16; ++k) dm = fmaxf(dm, red[k]);
      sflag = (dm < 0.001f) ? 1 : 0;
    }
    __syncthreads();
    const bool last = (sflag != 0) || (it == MAXIT - 1);

    // ---- KTu over my 64-col slab -> v (+fused final on last) ----
    {
      float acc8[8], w8[8];
      #pragma unroll
      for (int e = 0; e < 8; ++e) { acc8[e] = 0.f; w8[e] = 0.f; }
      #pragma unroll
      for (int t = 0; t < 8; ++t) {
        int i = w * 64 + t * 8 + r8;
        float ui = ulds[i];
        u16x8 k8 = *(const u16x8*)(Kb + (size_t)i * MTGT + bid * 64 + c8 * 8);
        #pragma unroll
        for (int e = 0; e < 8; ++e) {
          float k = bf2f(k8[e]);
          acc8[e] += k * ui;
          if (last) w8[e] += (k > 0.f) ? ui * k * (-0.1f * __logf(k)) : 0.f;
        }
      }
      #pragma unroll
      for (int e = 0; e < 8; ++e) {
        acc8[e] += __shfl_xor(acc8[e], 8, 64);
        acc8[e] += __shfl_xor(acc8[e], 16, 64);
        acc8[e] += __shfl_xor(acc8[e], 32, 64);
        if (last) {
          w8[e] += __shfl_xor(w8[e], 8, 64);
          w8[e] += __shfl_xor(w8[e], 16, 64);
          w8[e] += __shfl_xor(w8[e], 32, 64);
        }
      }
      if (r8 == 0) {
        #pragma unroll
        for (int e = 0; e < 8; ++e) {
          red[w * 68 + c8 * 8 + e] = acc8[e];
          wred[w * 68 + c8 * 8 + e] = w8[e];
        }
      }
      __syncthreads();
      if (tid < 64) {
        float tt = 0.f, wsum = 0.f;
        #pragma unroll
        for (int g = 0; g < 16; ++g) {
          tt += red[g * 68 + tid];
          if (last) wsum += wred[g * 68 + tid];
        }
        float vj = B_VAL / (tt + 1e-10f);
        vlds[tid] = vj;
        if (last) {
          float term = wsum * vj;
          #pragma unroll
          for (int off = 32; off > 0; off >>= 1) term += __shfl_down(term, off, 64);
          if (tid == 0) gstoref(&otp[bid], term);
        }
      }
    }
    __syncthreads();
    if (last) break;

    // ---- Kv partials with new v over my slab ----
    {
      #pragma unroll
      for (int t = 0; t < 8; ++t) {
        int i = w * 64 + t * 8 + r8;
        u16x8 k8 = *(const u16x8*)(Kb + (size_t)i * MTGT + bid * 64 + c8 * 8);
        float p = bf2f(k8[0]) * vlds[c8 * 8 + 0] + bf2f(k8[1]) * vlds[c8 * 8 + 1] +
                  bf2f(k8[2]) * vlds[c8 * 8 + 2] + bf2f(k8[3]) * vlds[c8 * 8 + 3] +
                  bf2f(k8[4]) * vlds[c8 * 8 + 4] + bf2f(k8[5]) * vlds[c8 * 8 + 5] +
                  bf2f(k8[6]) * vlds[c8 * 8 + 6] + bf2f(k8[7]) * vlds[c8 * 8 + 7];
        p += __shfl_xor(p, 1, 64); p += __shfl_xor(p, 2, 64); p += __shfl_xor(p, 4, 64);
        if (c8 == 0) gstoref(&Kvp[(size_t)bid * NSRC + i], p);
      }
    }
    grid_barrier(garr, root, gen, bt);
    // ---- stage2: reduce Kv partials for my 4 rows -> Kvf ----
    {
      float s = gloadf(&Kvp[(size_t)(tid >> 2) * NSRC + (bid << 2) + (tid & 3)]);
      s += __shfl_xor(s, 4, 64);  s += __shfl_xor(s, 8, 64);
      s += __shfl_xor(s, 16, 64); s += __shfl_xor(s, 32, 64);
      if (l < 4) red[w * 4 + l] = s;
      __syncthreads();
      if (tid < 4) {
        float t = 0.f;
        #pragma unroll
        for (int g = 0; g < 16; ++g) t += red[g * 4 + tid];
        gstoref(&Kvf[(bid << 2) + tid], t);
      }
    }
    grid_barrier(garr, root, gen, bt);
  }

  grid_barrier(garr, root, gen, bt);  // otp visible
  if (bid == 0) {
    float s = (tid < NBLK) ? gloadf(&otp[tid]) : 0.f;
    if (tid < NBLK) {
      #pragma unroll
      for (int off = 32; off > 0; off >>= 1) s += __shfl_down(s, off, 64);
      if (l == 0) red[w] = s;
    }
    __syncthreads();
    if (tid == 0) {
      float tot = red[0] + red[1] + red[2] + red[3];
      out[0] = sqrtf(tot / (float)(NSRC + MTGT) + 1e-8f);
    }
  }
}

// ---------------- launcher ----------------
extern "C" void kernel_launch(void* const* d_in, const int* in_sizes, int n_in,
                              void* d_out, int out_size, void* d_ws, size_t ws_size,
                              hipStream_t stream) {
  const float* src = (const float*)d_in[0];  // 1024 x 768
  const float* tgt = (const float*)d_in[1];  // 16384 x 768
  float* out = (float*)d_out;
  char* ws = (char*)d_ws;

  unsigned short* Ab = (unsigned short*)(ws);          // 1.5 MB bf16 A
  float* ssq = (float*)(ws + 1572864);                 // 4 KB
  float* Kvp = (float*)(ws + 1576960);                 // 1 MB [256][1024] partials
  float* Kvf = (float*)(ws + 2625536);                 // 4 KB
  float* otp = (float*)(ws + 2629632);                 // 1 KB
  unsigned* ctrl = (unsigned*)(ws + 2630656);          // 16 KB (zeroed by prep)
  unsigned* garr = ctrl;                               // [16] stride-64 words
  unsigned* root = ctrl + 1024;
  unsigned* gen  = ctrl + 1040;
  unsigned short* Kb = (unsigned short*)(ws + 4194304);  // 32 MB bf16 K

  ot_prep_kernel<<<256, 256, 0, stream>>>(src, Ab, ssq, ctrl);
  ot_gemm_kernel<<<NBLK, NTHR, 0, stream>>>(tgt, Ab, ssq, Kb, Kvp);
  ot_sinkhorn_kernel<<<NBLK, NTHR, 0, stream>>>(Kb, Kvp, Kvf, otp, out,
                                                garr, root, gen);
}